// Round 7
// baseline (195.896 us; speedup 1.0000x reference)
//
#include <hip/hip_runtime.h>
#include <hip/hip_bf16.h>
#include <math.h>

#define H 1024
#define V 50257
#define L 10

#define RPC 16                         // rows per chunk in out matvec
#define NCHUNK ((V + RPC - 1) / RPC)   // 3142
#define NBLK3 512                      // persistent blocks for K3 (2/CU guaranteed)

// ---------------- Workspace layout (floats) ----------------
#define WS_AW     0        // 16   attn weights
#define WS_GH     16       // 3072 W_hh @ h0 + b_hh
#define WS_HALF1  3104     // 1024 comb_W[:, :H] @ embedded   (no bias)
#define WS_M2T    4128     // 10*1024, layout [l][r]
#define WS_HNEW   14368    // 1024
#define WS_LOGITS 15392    // V -> ends 65649
#define WS_PAIRS  65664    // 2*NCHUNK -> ends 71948
#define WS_CNT    72000    // int[2]: [0]=chunk ticket, [1]=barrier arrivals

__device__ __forceinline__ float wave_reduce(float a) {
    #pragma unroll
    for (int off = 32; off > 0; off >>= 1) a += __shfl_down(a, off);
    return a;
}

__device__ __forceinline__ void lse_merge(float& m, float& s, float pm, float ps) {
    if (pm == -INFINITY) return;
    if (m == -INFINITY)  { m = pm; s = ps; }
    else if (pm <= m)    { s += ps * expf(pm - m); }
    else                 { s = s * expf(m - pm) + ps; m = pm; }
}

__device__ __forceinline__ float dot4(float4 a, float4 x) {
    return a.x * x.x + a.y * x.y + a.z * x.z + a.w * x.w;
}

// ========== K1: attn softmax | gh | half1 | M2  (513 blocks x 256) ==========
__global__ __launch_bounds__(256) void k_stage1(
    const int* __restrict__ idx, const float* __restrict__ hidden,
    const float* __restrict__ enc_outs, const float* __restrict__ emb,
    const float* __restrict__ attn_W, const float* __restrict__ attn_b,
    const float* __restrict__ W_hh, const float* __restrict__ b_hh,
    const float* __restrict__ comb_W,
    float* __restrict__ ws, float* __restrict__ aw_out)
{
    const int b = blockIdx.x, t = threadIdx.x;
    const int wave = t >> 6, lane = t & 63;
    const float* erow = emb + (size_t)idx[0] * H;

    if (b == 0) {
        // reset K3's counters for this call (stream-ordered before K3)
        if (t == 0) {
            ((int*)(ws + WS_CNT))[0] = NBLK3;  // next chunk ticket
            ((int*)(ws + WS_CNT))[1] = 0;      // barrier arrivals
        }
        __shared__ float s_w[16];
        const float4* e4 = (const float4*)erow;
        const float4* h4 = (const float4*)hidden;
        for (int l = wave; l < L; l += 4) {
            const float4* w4 = (const float4*)(attn_W + (size_t)l * 2 * H);
            float acc = 0.f;
            #pragma unroll
            for (int ii = 0; ii < 8; ++ii) {
                const int i = lane + 64 * ii;
                const float4 a = w4[i];
                const float4 x = (i < 256) ? e4[i] : h4[i - 256];
                acc += dot4(a, x);
            }
            acc = wave_reduce(acc);
            if (lane == 0) s_w[l] = acc + attn_b[l];
        }
        __syncthreads();
        if (t == 0) {
            float m = -1e30f;
            #pragma unroll
            for (int l = 0; l < L; ++l) m = fmaxf(m, s_w[l]);
            float s = 0.f;
            #pragma unroll
            for (int l = 0; l < L; ++l) { s_w[l] = expf(s_w[l] - m); s += s_w[l]; }
            const float inv = 1.f / s;
            #pragma unroll
            for (int l = 0; l < L; ++l) s_w[l] *= inv;
        }
        __syncthreads();
        if (t < L) { ws[WS_AW + t] = s_w[t]; aw_out[t] = s_w[t]; }
    } else if (b <= 192) {
        // gh = W_hh @ h0 + b_hh   (16 rows/block)
        const int r0 = (b - 1) * 16 + wave * 4;
        const float4* v4 = (const float4*)hidden;
        float4 hx[4];
        #pragma unroll
        for (int j = 0; j < 4; ++j) hx[j] = v4[lane + 64 * j];
        float a0 = 0.f, a1 = 0.f, a2 = 0.f, a3 = 0.f;
        const float4* w0 = (const float4*)(W_hh + (size_t)(r0 + 0) * H);
        const float4* w1 = (const float4*)(W_hh + (size_t)(r0 + 1) * H);
        const float4* w2 = (const float4*)(W_hh + (size_t)(r0 + 2) * H);
        const float4* w3 = (const float4*)(W_hh + (size_t)(r0 + 3) * H);
        #pragma unroll
        for (int j = 0; j < 4; ++j) {
            const int i = lane + 64 * j;
            a0 += dot4(w0[i], hx[j]); a1 += dot4(w1[i], hx[j]);
            a2 += dot4(w2[i], hx[j]); a3 += dot4(w3[i], hx[j]);
        }
        a0 = wave_reduce(a0); a1 = wave_reduce(a1);
        a2 = wave_reduce(a2); a3 = wave_reduce(a3);
        if (lane == 0) {
            ws[WS_GH + r0 + 0] = a0 + b_hh[r0 + 0];
            ws[WS_GH + r0 + 1] = a1 + b_hh[r0 + 1];
            ws[WS_GH + r0 + 2] = a2 + b_hh[r0 + 2];
            ws[WS_GH + r0 + 3] = a3 + b_hh[r0 + 3];
        }
    } else if (b <= 256) {
        // half1 = comb_W[:, :H] @ embedded   (16 rows/block)
        const int r0 = (b - 193) * 16 + wave * 4;
        const float4* e4 = (const float4*)erow;
        float4 ex[4];
        #pragma unroll
        for (int j = 0; j < 4; ++j) ex[j] = e4[lane + 64 * j];
        float a0 = 0.f, a1 = 0.f, a2 = 0.f, a3 = 0.f;
        const float4* w0 = (const float4*)(comb_W + (size_t)(r0 + 0) * 2 * H);
        const float4* w1 = (const float4*)(comb_W + (size_t)(r0 + 1) * 2 * H);
        const float4* w2 = (const float4*)(comb_W + (size_t)(r0 + 2) * 2 * H);
        const float4* w3 = (const float4*)(comb_W + (size_t)(r0 + 3) * 2 * H);
        #pragma unroll
        for (int j = 0; j < 4; ++j) {
            const int i = lane + 64 * j;
            a0 += dot4(w0[i], ex[j]); a1 += dot4(w1[i], ex[j]);
            a2 += dot4(w2[i], ex[j]); a3 += dot4(w3[i], ex[j]);
        }
        a0 = wave_reduce(a0); a1 = wave_reduce(a1);
        a2 = wave_reduce(a2); a3 = wave_reduce(a3);
        if (lane == 0) {
            ws[WS_HALF1 + r0 + 0] = a0; ws[WS_HALF1 + r0 + 1] = a1;
            ws[WS_HALF1 + r0 + 2] = a2; ws[WS_HALF1 + r0 + 3] = a3;
        }
    } else {
        // M2T[l][r] = dot(comb_W[r, H:2H], enc_outs[l]),  one row r per wave
        const int r = (b - 257) * 4 + wave;
        const float4* w4 = (const float4*)(comb_W + (size_t)r * 2 * H + H);
        float acc[L];
        #pragma unroll
        for (int l = 0; l < L; ++l) acc[l] = 0.f;
        #pragma unroll
        for (int j = 0; j < 4; ++j) {
            const int i = lane + 64 * j;
            const float4 w = w4[i];
            #pragma unroll
            for (int l = 0; l < L; ++l) {
                const float4 e = ((const float4*)(enc_outs + l * H))[i];
                acc[l] += dot4(w, e);
            }
        }
        #pragma unroll
        for (int l = 0; l < L; ++l) {
            const float r_ = wave_reduce(acc[l]);
            if (lane == 0) ws[WS_M2T + l * 1024 + r] = r_;
        }
    }
}

// ========== K2: x (redundant per block) + gi + GRU  (256 blocks x 256) ==========
__global__ __launch_bounds__(256) void k_gi_gru(
    const float* __restrict__ W_ih, const float* __restrict__ b_ih,
    const float* __restrict__ comb_b, const float* __restrict__ hidden,
    float* __restrict__ ws, float* __restrict__ h_out)
{
    __shared__ float sx[1024];
    const int t = threadIdx.x;
    #pragma unroll
    for (int q = 0; q < 4; ++q) {
        const int e = t + q * 256;
        float acc = ws[WS_HALF1 + e] + comb_b[e];
        #pragma unroll
        for (int l = 0; l < L; ++l)
            acc += ws[WS_M2T + l * 1024 + e] * ws[WS_AW + l];
        sx[e] = fmaxf(acc, 0.f);
    }
    __syncthreads();
    const int wave = t >> 6, lane = t & 63;
    const int u = blockIdx.x * 4 + wave;
    const float4* x4 = (const float4*)sx;
    const float4* w0 = (const float4*)(W_ih + (size_t)u * H);
    const float4* w1 = (const float4*)(W_ih + (size_t)(H + u) * H);
    const float4* w2 = (const float4*)(W_ih + (size_t)(2 * H + u) * H);
    float a0 = 0.f, a1 = 0.f, a2 = 0.f;
    #pragma unroll
    for (int q = 0; q < 4; ++q) {
        const int i = lane + 64 * q;
        const float4 x = x4[i];
        a0 += dot4(w0[i], x);
        a1 += dot4(w1[i], x);
        a2 += dot4(w2[i], x);
    }
    a0 = wave_reduce(a0); a1 = wave_reduce(a1); a2 = wave_reduce(a2);
    if (lane == 0) {
        const float ir  = a0 + b_ih[u];
        const float iz  = a1 + b_ih[H + u];
        const float in_ = a2 + b_ih[2 * H + u];
        const float hr = ws[WS_GH + u];
        const float hz = ws[WS_GH + H + u];
        const float hn = ws[WS_GH + 2 * H + u];
        const float r = 1.f / (1.f + expf(-(ir + hr)));
        const float z = 1.f / (1.f + expf(-(iz + hz)));
        const float n = tanhf(in_ + r * hn);
        const float h = (1.f - z) * n + z * hidden[u];
        ws[WS_HNEW + u] = h;
        h_out[u] = h;
    }
}

// ========== K3: persistent out matvec + device barrier + merge + write ==========
// 512 blocks x 256 thr, 2 blocks/CU co-resident (occupancy-guaranteed), so the
// software grid barrier is deadlock-free. Chunk->pair slot is fixed, so dynamic
// ticketing does not affect the result.
__global__ __launch_bounds__(256) void k_out_full(
    const float* __restrict__ out_W, const float* __restrict__ out_b,
    float* __restrict__ ws, float* __restrict__ out)
{
    __shared__ float sm[4], ss[4];
    __shared__ float rm[256], rs[256];
    __shared__ int s_c;
    const int b = blockIdx.x, t = threadIdx.x;
    const int wave = t >> 6, lane = t & 63;
    int* cnt = (int*)(ws + WS_CNT);
    float* logits = ws + WS_LOGITS;
    float* pairs  = ws + WS_PAIRS;

    const float4* v4 = (const float4*)(ws + WS_HNEW);
    float4 hx[4];
    #pragma unroll
    for (int j = 0; j < 4; ++j) hx[j] = v4[lane + 64 * j];

    // ---- chunk loop (dynamic ticket; first chunk = own block id) ----
    int c = b;
    while (c < NCHUNK) {
        const int base = c * RPC + wave * 4;
        float wm = -INFINITY, wsum = 0.f;
        #pragma unroll
        for (int k = 0; k < 4; ++k) {
            const int row = base + k;
            if (row < V) {
                const float4* w4 = (const float4*)(out_W + (size_t)row * H);
                float acc = 0.f;
                #pragma unroll
                for (int j = 0; j < 4; ++j) acc += dot4(w4[lane + 64 * j], hx[j]);
                acc = wave_reduce(acc);
                if (lane == 0) {
                    const float val = acc + out_b[row];
                    logits[row] = val;
                    lse_merge(wm, wsum, val, 1.f);
                }
            }
        }
        if (lane == 0) { sm[wave] = wm; ss[wave] = wsum; }
        if (t == 0) s_c = atomicAdd(&cnt[0], 1);
        __syncthreads();
        if (t == 0) {
            float m = -INFINITY, s = 0.f;
            #pragma unroll
            for (int w = 0; w < 4; ++w) lse_merge(m, s, sm[w], ss[w]);
            pairs[2 * c] = m; pairs[2 * c + 1] = s;
        }
        const int cn = s_c;
        __syncthreads();
        c = cn;
    }

    // ---- software grid barrier (all 512 blocks co-resident) ----
    __threadfence();
    __syncthreads();
    if (t == 0) {
        atomicAdd(&cnt[1], 1);
        while (atomicAdd(&cnt[1], 0) < NBLK3) __builtin_amdgcn_s_sleep(2);
    }
    __syncthreads();
    __threadfence();

    // ---- redundant pair merge + write (only blocks covering V) ----
    if (b * 256 < V) {
        float m = -INFINITY, s = 0.f;
        for (int i = t; i < NCHUNK; i += 256)
            lse_merge(m, s, pairs[2 * i], pairs[2 * i + 1]);
        rm[t] = m; rs[t] = s;
        __syncthreads();
        for (int k = 128; k > 0; k >>= 1) {
            if (t < k) {
                float mm = rm[t], ssv = rs[t];
                lse_merge(mm, ssv, rm[t + k], rs[t + k]);
                rm[t] = mm; rs[t] = ssv;
            }
            __syncthreads();
        }
        const float M = rm[0], LS = logf(rs[0]);
        const int i = b * 256 + t;
        if (i < V) out[i] = logits[i] - M - LS;
    }
}

extern "C" void kernel_launch(void* const* d_in, const int* in_sizes, int n_in,
                              void* d_out, int out_size, void* d_ws, size_t ws_size,
                              hipStream_t stream) {
    const int*   idx      = (const int*)  d_in[0];
    const float* hidden   = (const float*)d_in[1];
    const float* enc_outs = (const float*)d_in[3];
    const float* emb      = (const float*)d_in[4];
    const float* attn_W   = (const float*)d_in[5];
    const float* attn_b   = (const float*)d_in[6];
    const float* comb_W   = (const float*)d_in[7];
    const float* comb_b   = (const float*)d_in[8];
    const float* W_ih     = (const float*)d_in[9];
    const float* W_hh     = (const float*)d_in[10];
    const float* b_ih     = (const float*)d_in[11];
    const float* b_hh     = (const float*)d_in[12];
    const float* out_W    = (const float*)d_in[13];
    const float* out_b    = (const float*)d_in[14];

    float* ws  = (float*)d_ws;
    float* out = (float*)d_out;   // [0,V) log-probs | [V,V+H) h_new | [V+H,+L) attn_w

    // K1: attn softmax | gh | half1 | M2  (+ resets K3 counters)
    k_stage1<<<513, 256, 0, stream>>>(idx, hidden, enc_outs, emb,
                                      attn_W, attn_b, W_hh, b_hh, comb_W,
                                      ws, out + V + H);
    // K2: x (redundant/block) + gi + GRU -> h_new
    k_gi_gru<<<256, 256, 0, stream>>>(W_ih, b_ih, comb_b, hidden, ws, out + V);
    // K3: persistent matvec + barrier + merge + write (fused K3+K4)
    k_out_full<<<NBLK3, 256, 0, stream>>>(out_W, out_b, ws, out);
}

// Round 8
// 63.236 us; speedup vs baseline: 3.0979x; 3.0979x over previous
//
#include <hip/hip_runtime.h>
#include <hip/hip_bf16.h>
#include <math.h>

#define H 1024
#define V 50257
#define L 10

#define RPC 8                          // rows per chunk in out_mv (2 rows/wave)
#define NCHUNK ((V + RPC - 1) / RPC)   // 6283

// ---------------- Workspace layout (floats) ----------------
#define WS_AW     0        // 16   attn weights
#define WS_GH     16       // 3072 W_hh @ h0 + b_hh
#define WS_HALF1  3104     // 1024 comb_W[:, :H] @ embedded   (no bias)
#define WS_M2T    4128     // 10*1024, layout [l][r]
#define WS_HNEW   14368    // 1024
#define WS_LOGITS 15392    // V -> ends 65649
#define WS_PAIRS  65664    // 2*NCHUNK = 12566 -> ends 78230 (~313 KB)

__device__ __forceinline__ float wave_reduce(float a) {
    #pragma unroll
    for (int off = 32; off > 0; off >>= 1) a += __shfl_down(a, off);
    return a;
}

__device__ __forceinline__ void lse_merge(float& m, float& s, float pm, float ps) {
    if (pm == -INFINITY) return;
    if (m == -INFINITY)  { m = pm; s = ps; }
    else if (pm <= m)    { s += ps * expf(pm - m); }
    else                 { s = s * expf(m - pm) + ps; m = pm; }
}

__device__ __forceinline__ float dot4(float4 a, float4 x) {
    return a.x * x.x + a.y * x.y + a.z * x.z + a.w * x.w;
}

// ========== K1: attn softmax | gh | half1 | M2  (513 blocks x 256) ==========
__global__ __launch_bounds__(256) void k_stage1(
    const int* __restrict__ idx, const float* __restrict__ hidden,
    const float* __restrict__ enc_outs, const float* __restrict__ emb,
    const float* __restrict__ attn_W, const float* __restrict__ attn_b,
    const float* __restrict__ W_hh, const float* __restrict__ b_hh,
    const float* __restrict__ comb_W,
    float* __restrict__ ws, float* __restrict__ aw_out)
{
    const int b = blockIdx.x, t = threadIdx.x;
    const int wave = t >> 6, lane = t & 63;
    const float* erow = emb + (size_t)idx[0] * H;

    if (b == 0) {
        __shared__ float s_w[16];
        const float4* e4 = (const float4*)erow;
        const float4* h4 = (const float4*)hidden;
        for (int l = wave; l < L; l += 4) {
            const float4* w4 = (const float4*)(attn_W + (size_t)l * 2 * H);
            float acc = 0.f;
            #pragma unroll
            for (int ii = 0; ii < 8; ++ii) {
                const int i = lane + 64 * ii;
                const float4 a = w4[i];
                const float4 x = (i < 256) ? e4[i] : h4[i - 256];
                acc += dot4(a, x);
            }
            acc = wave_reduce(acc);
            if (lane == 0) s_w[l] = acc + attn_b[l];
        }
        __syncthreads();
        if (t == 0) {
            float m = -1e30f;
            #pragma unroll
            for (int l = 0; l < L; ++l) m = fmaxf(m, s_w[l]);
            float s = 0.f;
            #pragma unroll
            for (int l = 0; l < L; ++l) { s_w[l] = expf(s_w[l] - m); s += s_w[l]; }
            const float inv = 1.f / s;
            #pragma unroll
            for (int l = 0; l < L; ++l) s_w[l] *= inv;
        }
        __syncthreads();
        if (t < L) { ws[WS_AW + t] = s_w[t]; aw_out[t] = s_w[t]; }
    } else if (b <= 192) {
        // gh = W_hh @ h0 + b_hh   (16 rows/block)
        const int r0 = (b - 1) * 16 + wave * 4;
        const float4* v4 = (const float4*)hidden;
        float4 hx[4];
        #pragma unroll
        for (int j = 0; j < 4; ++j) hx[j] = v4[lane + 64 * j];
        float a0 = 0.f, a1 = 0.f, a2 = 0.f, a3 = 0.f;
        const float4* w0 = (const float4*)(W_hh + (size_t)(r0 + 0) * H);
        const float4* w1 = (const float4*)(W_hh + (size_t)(r0 + 1) * H);
        const float4* w2 = (const float4*)(W_hh + (size_t)(r0 + 2) * H);
        const float4* w3 = (const float4*)(W_hh + (size_t)(r0 + 3) * H);
        #pragma unroll
        for (int j = 0; j < 4; ++j) {
            const int i = lane + 64 * j;
            a0 += dot4(w0[i], hx[j]); a1 += dot4(w1[i], hx[j]);
            a2 += dot4(w2[i], hx[j]); a3 += dot4(w3[i], hx[j]);
        }
        a0 = wave_reduce(a0); a1 = wave_reduce(a1);
        a2 = wave_reduce(a2); a3 = wave_reduce(a3);
        if (lane == 0) {
            ws[WS_GH + r0 + 0] = a0 + b_hh[r0 + 0];
            ws[WS_GH + r0 + 1] = a1 + b_hh[r0 + 1];
            ws[WS_GH + r0 + 2] = a2 + b_hh[r0 + 2];
            ws[WS_GH + r0 + 3] = a3 + b_hh[r0 + 3];
        }
    } else if (b <= 256) {
        // half1 = comb_W[:, :H] @ embedded   (16 rows/block)
        const int r0 = (b - 193) * 16 + wave * 4;
        const float4* e4 = (const float4*)erow;
        float4 ex[4];
        #pragma unroll
        for (int j = 0; j < 4; ++j) ex[j] = e4[lane + 64 * j];
        float a0 = 0.f, a1 = 0.f, a2 = 0.f, a3 = 0.f;
        const float4* w0 = (const float4*)(comb_W + (size_t)(r0 + 0) * 2 * H);
        const float4* w1 = (const float4*)(comb_W + (size_t)(r0 + 1) * 2 * H);
        const float4* w2 = (const float4*)(comb_W + (size_t)(r0 + 2) * 2 * H);
        const float4* w3 = (const float4*)(comb_W + (size_t)(r0 + 3) * 2 * H);
        #pragma unroll
        for (int j = 0; j < 4; ++j) {
            const int i = lane + 64 * j;
            a0 += dot4(w0[i], ex[j]); a1 += dot4(w1[i], ex[j]);
            a2 += dot4(w2[i], ex[j]); a3 += dot4(w3[i], ex[j]);
        }
        a0 = wave_reduce(a0); a1 = wave_reduce(a1);
        a2 = wave_reduce(a2); a3 = wave_reduce(a3);
        if (lane == 0) {
            ws[WS_HALF1 + r0 + 0] = a0; ws[WS_HALF1 + r0 + 1] = a1;
            ws[WS_HALF1 + r0 + 2] = a2; ws[WS_HALF1 + r0 + 3] = a3;
        }
    } else {
        // M2T[l][r] = dot(comb_W[r, H:2H], enc_outs[l]),  one row r per wave
        const int r = (b - 257) * 4 + wave;
        const float4* w4 = (const float4*)(comb_W + (size_t)r * 2 * H + H);
        float acc[L];
        #pragma unroll
        for (int l = 0; l < L; ++l) acc[l] = 0.f;
        #pragma unroll
        for (int j = 0; j < 4; ++j) {
            const int i = lane + 64 * j;
            const float4 w = w4[i];
            #pragma unroll
            for (int l = 0; l < L; ++l) {
                const float4 e = ((const float4*)(enc_outs + l * H))[i];
                acc[l] += dot4(w, e);
            }
        }
        #pragma unroll
        for (int l = 0; l < L; ++l) {
            const float r_ = wave_reduce(acc[l]);
            if (lane == 0) ws[WS_M2T + l * 1024 + r] = r_;
        }
    }
}

// ========== K2: x (redundant per block) + gi + GRU  (256 blocks x 256) ==========
__global__ __launch_bounds__(256) void k_gi_gru(
    const float* __restrict__ W_ih, const float* __restrict__ b_ih,
    const float* __restrict__ comb_b, const float* __restrict__ hidden,
    float* __restrict__ ws, float* __restrict__ h_out)
{
    __shared__ float sx[1024];
    const int t = threadIdx.x;
    #pragma unroll
    for (int q = 0; q < 4; ++q) {
        const int e = t + q * 256;
        float acc = ws[WS_HALF1 + e] + comb_b[e];
        #pragma unroll
        for (int l = 0; l < L; ++l)
            acc += ws[WS_M2T + l * 1024 + e] * ws[WS_AW + l];
        sx[e] = fmaxf(acc, 0.f);
    }
    __syncthreads();
    const int wave = t >> 6, lane = t & 63;
    const int u = blockIdx.x * 4 + wave;
    const float4* x4 = (const float4*)sx;
    const float4* w0 = (const float4*)(W_ih + (size_t)u * H);
    const float4* w1 = (const float4*)(W_ih + (size_t)(H + u) * H);
    const float4* w2 = (const float4*)(W_ih + (size_t)(2 * H + u) * H);
    float a0 = 0.f, a1 = 0.f, a2 = 0.f;
    #pragma unroll
    for (int q = 0; q < 4; ++q) {
        const int i = lane + 64 * q;
        const float4 x = x4[i];
        a0 += dot4(w0[i], x);
        a1 += dot4(w1[i], x);
        a2 += dot4(w2[i], x);
    }
    a0 = wave_reduce(a0); a1 = wave_reduce(a1); a2 = wave_reduce(a2);
    if (lane == 0) {
        const float ir  = a0 + b_ih[u];
        const float iz  = a1 + b_ih[H + u];
        const float in_ = a2 + b_ih[2 * H + u];
        const float hr = ws[WS_GH + u];
        const float hz = ws[WS_GH + H + u];
        const float hn = ws[WS_GH + 2 * H + u];
        const float r = 1.f / (1.f + expf(-(ir + hr)));
        const float z = 1.f / (1.f + expf(-(iz + hz)));
        const float n = tanhf(in_ + r * hn);
        const float h = (1.f - z) * n + z * hidden[u];
        ws[WS_HNEW + u] = h;
        h_out[u] = h;
    }
}

// ========== K3: logits = out_W @ h_new + out_b + per-chunk LSE pairs ==========
// R6 inner loop, RPC=8: 2 rows/wave, 6283 blocks (smaller tail granularity)
__global__ __launch_bounds__(256) void k_out_mv(
    const float* __restrict__ out_W, const float* __restrict__ out_b,
    const float* __restrict__ ws_in, float* __restrict__ logits,
    float* __restrict__ pairs)
{
    __shared__ float sm[4], ss[4];
    const int wave = threadIdx.x >> 6, lane = threadIdx.x & 63;
    const int base = blockIdx.x * RPC + wave * 2;
    const float4* v4 = (const float4*)(ws_in + WS_HNEW);
    float4 hx[4];
    #pragma unroll
    for (int j = 0; j < 4; ++j) hx[j] = v4[lane + 64 * j];
    float wm = -INFINITY, wsum = 0.f;
    #pragma unroll
    for (int k = 0; k < 2; ++k) {
        const int row = base + k;
        if (row < V) {
            const float4* w4 = (const float4*)(out_W + (size_t)row * H);
            float acc = 0.f;
            #pragma unroll
            for (int j = 0; j < 4; ++j) acc += dot4(w4[lane + 64 * j], hx[j]);
            acc = wave_reduce(acc);
            if (lane == 0) {
                const float val = acc + out_b[row];
                logits[row] = val;
                lse_merge(wm, wsum, val, 1.f);
            }
        }
    }
    if (lane == 0) { sm[wave] = wm; ss[wave] = wsum; }
    __syncthreads();
    if (threadIdx.x == 0) {
        float m = -INFINITY, s = 0.f;
        #pragma unroll
        for (int w = 0; w < 4; ++w) lse_merge(m, s, sm[w], ss[w]);
        pairs[2 * blockIdx.x] = m; pairs[2 * blockIdx.x + 1] = s;
    }
}

// ========== K4: redundant pair merge + write log-softmax ==========
__global__ __launch_bounds__(256) void k_write(
    const float* __restrict__ logits, const float* __restrict__ pairs,
    float* __restrict__ out)
{
    __shared__ float sm[256], ss[256];
    const int t = threadIdx.x;
    float m = -INFINITY, s = 0.f;
    for (int i = t; i < NCHUNK; i += 256) lse_merge(m, s, pairs[2 * i], pairs[2 * i + 1]);
    sm[t] = m; ss[t] = s; __syncthreads();
    for (int k = 128; k > 0; k >>= 1) {
        if (t < k) {
            float mm = sm[t], ssv = ss[t];
            lse_merge(mm, ssv, sm[t + k], ss[t + k]);
            sm[t] = mm; ss[t] = ssv;
        }
        __syncthreads();
    }
    const float M = sm[0], LS = logf(ss[0]);
    const int i = blockIdx.x * 256 + t;
    if (i < V) out[i] = logits[i] - M - LS;
}

extern "C" void kernel_launch(void* const* d_in, const int* in_sizes, int n_in,
                              void* d_out, int out_size, void* d_ws, size_t ws_size,
                              hipStream_t stream) {
    const int*   idx      = (const int*)  d_in[0];
    const float* hidden   = (const float*)d_in[1];
    const float* enc_outs = (const float*)d_in[3];
    const float* emb      = (const float*)d_in[4];
    const float* attn_W   = (const float*)d_in[5];
    const float* attn_b   = (const float*)d_in[6];
    const float* comb_W   = (const float*)d_in[7];
    const float* comb_b   = (const float*)d_in[8];
    const float* W_ih     = (const float*)d_in[9];
    const float* W_hh     = (const float*)d_in[10];
    const float* b_ih     = (const float*)d_in[11];
    const float* b_hh     = (const float*)d_in[12];
    const float* out_W    = (const float*)d_in[13];
    const float* out_b    = (const float*)d_in[14];

    float* ws  = (float*)d_ws;
    float* out = (float*)d_out;   // [0,V) log-probs | [V,V+H) h_new | [V+H,+L) attn_w

    // K1: attn softmax | gh | half1 | M2   (all independent given inputs)
    k_stage1<<<513, 256, 0, stream>>>(idx, hidden, enc_outs, emb,
                                      attn_W, attn_b, W_hh, b_hh, comb_W,
                                      ws, out + V + H);
    // K2: x (redundant/block) + gi + GRU -> h_new
    k_gi_gru<<<256, 256, 0, stream>>>(W_ih, b_ih, comb_b, hidden, ws, out + V);
    // K3: big matvec + per-chunk LSE pairs  (RPC=8 -> 6283 blocks)
    k_out_mv<<<NCHUNK, 256, 0, stream>>>(out_W, out_b, ws,
                                         ws + WS_LOGITS, ws + WS_PAIRS);
    // K4: merge pairs + write log-softmax
    k_write<<<(V + 255) / 256, 256, 0, stream>>>(ws + WS_LOGITS, ws + WS_PAIRS, out);
}

// Round 9
// 59.531 us; speedup vs baseline: 3.2907x; 1.0622x over previous
//
#include <hip/hip_runtime.h>
#include <hip/hip_bf16.h>
#include <math.h>

#define H 1024
#define V 50257
#define L 10

#define RPC 16                         // rows per chunk in out_mv (4 rows/wave)
#define NCHUNK ((V + RPC - 1) / RPC)   // 3142
#define NBLK3 2048                     // resident blocks for K3, grid-stride

// ---------------- Workspace layout (floats) ----------------
#define WS_AW     0        // 16   attn weights
#define WS_GH     16       // 3072 W_hh @ h0 + b_hh
#define WS_HALF1  3104     // 1024 comb_W[:, :H] @ embedded   (no bias)
#define WS_M2T    4128     // 10*1024, layout [l][r]
#define WS_HNEW   14368    // 1024
#define WS_LOGITS 15392    // V -> ends 65649
#define WS_PAIRS  65664    // 2*NCHUNK -> ends 71948

__device__ __forceinline__ float wave_reduce(float a) {
    #pragma unroll
    for (int off = 32; off > 0; off >>= 1) a += __shfl_down(a, off);
    return a;
}

__device__ __forceinline__ void lse_merge(float& m, float& s, float pm, float ps) {
    if (pm == -INFINITY) return;
    if (m == -INFINITY)  { m = pm; s = ps; }
    else if (pm <= m)    { s += ps * expf(pm - m); }
    else                 { s = s * expf(m - pm) + ps; m = pm; }
}

__device__ __forceinline__ float dot4(float4 a, float4 x) {
    return a.x * x.x + a.y * x.y + a.z * x.z + a.w * x.w;
}

// ========== K1: attn softmax | gh | half1 | M2  (513 blocks x 256) ==========
__global__ __launch_bounds__(256) void k_stage1(
    const int* __restrict__ idx, const float* __restrict__ hidden,
    const float* __restrict__ enc_outs, const float* __restrict__ emb,
    const float* __restrict__ attn_W, const float* __restrict__ attn_b,
    const float* __restrict__ W_hh, const float* __restrict__ b_hh,
    const float* __restrict__ comb_W,
    float* __restrict__ ws, float* __restrict__ aw_out)
{
    const int b = blockIdx.x, t = threadIdx.x;
    const int wave = t >> 6, lane = t & 63;
    const float* erow = emb + (size_t)idx[0] * H;

    if (b == 0) {
        __shared__ float s_w[16];
        const float4* e4 = (const float4*)erow;
        const float4* h4 = (const float4*)hidden;
        for (int l = wave; l < L; l += 4) {
            const float4* w4 = (const float4*)(attn_W + (size_t)l * 2 * H);
            float acc = 0.f;
            #pragma unroll
            for (int ii = 0; ii < 8; ++ii) {
                const int i = lane + 64 * ii;
                const float4 a = w4[i];
                const float4 x = (i < 256) ? e4[i] : h4[i - 256];
                acc += dot4(a, x);
            }
            acc = wave_reduce(acc);
            if (lane == 0) s_w[l] = acc + attn_b[l];
        }
        __syncthreads();
        if (t == 0) {
            float m = -1e30f;
            #pragma unroll
            for (int l = 0; l < L; ++l) m = fmaxf(m, s_w[l]);
            float s = 0.f;
            #pragma unroll
            for (int l = 0; l < L; ++l) { s_w[l] = expf(s_w[l] - m); s += s_w[l]; }
            const float inv = 1.f / s;
            #pragma unroll
            for (int l = 0; l < L; ++l) s_w[l] *= inv;
        }
        __syncthreads();
        if (t < L) { ws[WS_AW + t] = s_w[t]; aw_out[t] = s_w[t]; }
    } else if (b <= 192) {
        // gh = W_hh @ h0 + b_hh   (16 rows/block)
        const int r0 = (b - 1) * 16 + wave * 4;
        const float4* v4 = (const float4*)hidden;
        float4 hx[4];
        #pragma unroll
        for (int j = 0; j < 4; ++j) hx[j] = v4[lane + 64 * j];
        float a0 = 0.f, a1 = 0.f, a2 = 0.f, a3 = 0.f;
        const float4* w0 = (const float4*)(W_hh + (size_t)(r0 + 0) * H);
        const float4* w1 = (const float4*)(W_hh + (size_t)(r0 + 1) * H);
        const float4* w2 = (const float4*)(W_hh + (size_t)(r0 + 2) * H);
        const float4* w3 = (const float4*)(W_hh + (size_t)(r0 + 3) * H);
        #pragma unroll
        for (int j = 0; j < 4; ++j) {
            const int i = lane + 64 * j;
            a0 += dot4(w0[i], hx[j]); a1 += dot4(w1[i], hx[j]);
            a2 += dot4(w2[i], hx[j]); a3 += dot4(w3[i], hx[j]);
        }
        a0 = wave_reduce(a0); a1 = wave_reduce(a1);
        a2 = wave_reduce(a2); a3 = wave_reduce(a3);
        if (lane == 0) {
            ws[WS_GH + r0 + 0] = a0 + b_hh[r0 + 0];
            ws[WS_GH + r0 + 1] = a1 + b_hh[r0 + 1];
            ws[WS_GH + r0 + 2] = a2 + b_hh[r0 + 2];
            ws[WS_GH + r0 + 3] = a3 + b_hh[r0 + 3];
        }
    } else if (b <= 256) {
        // half1 = comb_W[:, :H] @ embedded   (16 rows/block)
        const int r0 = (b - 193) * 16 + wave * 4;
        const float4* e4 = (const float4*)erow;
        float4 ex[4];
        #pragma unroll
        for (int j = 0; j < 4; ++j) ex[j] = e4[lane + 64 * j];
        float a0 = 0.f, a1 = 0.f, a2 = 0.f, a3 = 0.f;
        const float4* w0 = (const float4*)(comb_W + (size_t)(r0 + 0) * 2 * H);
        const float4* w1 = (const float4*)(comb_W + (size_t)(r0 + 1) * 2 * H);
        const float4* w2 = (const float4*)(comb_W + (size_t)(r0 + 2) * 2 * H);
        const float4* w3 = (const float4*)(comb_W + (size_t)(r0 + 3) * 2 * H);
        #pragma unroll
        for (int j = 0; j < 4; ++j) {
            const int i = lane + 64 * j;
            a0 += dot4(w0[i], ex[j]); a1 += dot4(w1[i], ex[j]);
            a2 += dot4(w2[i], ex[j]); a3 += dot4(w3[i], ex[j]);
        }
        a0 = wave_reduce(a0); a1 = wave_reduce(a1);
        a2 = wave_reduce(a2); a3 = wave_reduce(a3);
        if (lane == 0) {
            ws[WS_HALF1 + r0 + 0] = a0; ws[WS_HALF1 + r0 + 1] = a1;
            ws[WS_HALF1 + r0 + 2] = a2; ws[WS_HALF1 + r0 + 3] = a3;
        }
    } else {
        // M2T[l][r] = dot(comb_W[r, H:2H], enc_outs[l]),  one row r per wave
        const int r = (b - 257) * 4 + wave;
        const float4* w4 = (const float4*)(comb_W + (size_t)r * 2 * H + H);
        float acc[L];
        #pragma unroll
        for (int l = 0; l < L; ++l) acc[l] = 0.f;
        #pragma unroll
        for (int j = 0; j < 4; ++j) {
            const int i = lane + 64 * j;
            const float4 w = w4[i];
            #pragma unroll
            for (int l = 0; l < L; ++l) {
                const float4 e = ((const float4*)(enc_outs + l * H))[i];
                acc[l] += dot4(w, e);
            }
        }
        #pragma unroll
        for (int l = 0; l < L; ++l) {
            const float r_ = wave_reduce(acc[l]);
            if (lane == 0) ws[WS_M2T + l * 1024 + r] = r_;
        }
    }
}

// ========== K2: x (redundant per block) + gi + GRU  (256 blocks x 256) ==========
__global__ __launch_bounds__(256) void k_gi_gru(
    const float* __restrict__ W_ih, const float* __restrict__ b_ih,
    const float* __restrict__ comb_b, const float* __restrict__ hidden,
    float* __restrict__ ws, float* __restrict__ h_out)
{
    __shared__ float sx[1024];
    const int t = threadIdx.x;
    #pragma unroll
    for (int q = 0; q < 4; ++q) {
        const int e = t + q * 256;
        float acc = ws[WS_HALF1 + e] + comb_b[e];
        #pragma unroll
        for (int l = 0; l < L; ++l)
            acc += ws[WS_M2T + l * 1024 + e] * ws[WS_AW + l];
        sx[e] = fmaxf(acc, 0.f);
    }
    __syncthreads();
    const int wave = t >> 6, lane = t & 63;
    const int u = blockIdx.x * 4 + wave;
    const float4* x4 = (const float4*)sx;
    const float4* w0 = (const float4*)(W_ih + (size_t)u * H);
    const float4* w1 = (const float4*)(W_ih + (size_t)(H + u) * H);
    const float4* w2 = (const float4*)(W_ih + (size_t)(2 * H + u) * H);
    float a0 = 0.f, a1 = 0.f, a2 = 0.f;
    #pragma unroll
    for (int q = 0; q < 4; ++q) {
        const int i = lane + 64 * q;
        const float4 x = x4[i];
        a0 += dot4(w0[i], x);
        a1 += dot4(w1[i], x);
        a2 += dot4(w2[i], x);
    }
    a0 = wave_reduce(a0); a1 = wave_reduce(a1); a2 = wave_reduce(a2);
    if (lane == 0) {
        const float ir  = a0 + b_ih[u];
        const float iz  = a1 + b_ih[H + u];
        const float in_ = a2 + b_ih[2 * H + u];
        const float hr = ws[WS_GH + u];
        const float hz = ws[WS_GH + H + u];
        const float hn = ws[WS_GH + 2 * H + u];
        const float r = 1.f / (1.f + expf(-(ir + hr)));
        const float z = 1.f / (1.f + expf(-(iz + hz)));
        const float n = tanhf(in_ + r * hn);
        const float h = (1.f - z) * n + z * hidden[u];
        ws[WS_HNEW + u] = h;
        h_out[u] = h;
    }
}

// ========== K3: out matvec, 2048 blocks grid-stride over 3142 chunks ==========
// Inner chunk body identical to R6's proven k_out_mv; hx loaded once per block.
__global__ __launch_bounds__(256) void k_out_mv(
    const float* __restrict__ out_W, const float* __restrict__ out_b,
    const float* __restrict__ ws_in, float* __restrict__ logits,
    float* __restrict__ pairs)
{
    __shared__ float sm[4], ss[4];
    const int wave = threadIdx.x >> 6, lane = threadIdx.x & 63;
    const float4* v4 = (const float4*)(ws_in + WS_HNEW);
    float4 hx[4];
    #pragma unroll
    for (int j = 0; j < 4; ++j) hx[j] = v4[lane + 64 * j];

    for (int c = blockIdx.x; c < NCHUNK; c += NBLK3) {
        const int base = c * RPC + wave * 4;
        float wm = -INFINITY, wsum = 0.f;
        #pragma unroll
        for (int k = 0; k < 4; ++k) {
            const int row = base + k;
            if (row < V) {
                const float4* w4 = (const float4*)(out_W + (size_t)row * H);
                float acc = 0.f;
                #pragma unroll
                for (int j = 0; j < 4; ++j) acc += dot4(w4[lane + 64 * j], hx[j]);
                acc = wave_reduce(acc);
                if (lane == 0) {
                    const float val = acc + out_b[row];
                    logits[row] = val;
                    lse_merge(wm, wsum, val, 1.f);
                }
            }
        }
        if (lane == 0) { sm[wave] = wm; ss[wave] = wsum; }
        __syncthreads();
        if (threadIdx.x == 0) {
            float m = -INFINITY, s = 0.f;
            #pragma unroll
            for (int w = 0; w < 4; ++w) lse_merge(m, s, sm[w], ss[w]);
            pairs[2 * c] = m; pairs[2 * c + 1] = s;
        }
        __syncthreads();
    }
}

// ========== K4: redundant pair merge + write log-softmax ==========
__global__ __launch_bounds__(256) void k_write(
    const float* __restrict__ logits, const float* __restrict__ pairs,
    float* __restrict__ out)
{
    __shared__ float sm[256], ss[256];
    const int t = threadIdx.x;
    float m = -INFINITY, s = 0.f;
    for (int i = t; i < NCHUNK; i += 256) lse_merge(m, s, pairs[2 * i], pairs[2 * i + 1]);
    sm[t] = m; ss[t] = s; __syncthreads();
    for (int k = 128; k > 0; k >>= 1) {
        if (t < k) {
            float mm = sm[t], ssv = ss[t];
            lse_merge(mm, ssv, sm[t + k], ss[t + k]);
            sm[t] = mm; ss[t] = ssv;
        }
        __syncthreads();
    }
    const float M = sm[0], LS = logf(ss[0]);
    const int i = blockIdx.x * 256 + t;
    if (i < V) out[i] = logits[i] - M - LS;
}

extern "C" void kernel_launch(void* const* d_in, const int* in_sizes, int n_in,
                              void* d_out, int out_size, void* d_ws, size_t ws_size,
                              hipStream_t stream) {
    const int*   idx      = (const int*)  d_in[0];
    const float* hidden   = (const float*)d_in[1];
    const float* enc_outs = (const float*)d_in[3];
    const float* emb      = (const float*)d_in[4];
    const float* attn_W   = (const float*)d_in[5];
    const float* attn_b   = (const float*)d_in[6];
    const float* comb_W   = (const float*)d_in[7];
    const float* comb_b   = (const float*)d_in[8];
    const float* W_ih     = (const float*)d_in[9];
    const float* W_hh     = (const float*)d_in[10];
    const float* b_ih     = (const float*)d_in[11];
    const float* b_hh     = (const float*)d_in[12];
    const float* out_W    = (const float*)d_in[13];
    const float* out_b    = (const float*)d_in[14];

    float* ws  = (float*)d_ws;
    float* out = (float*)d_out;   // [0,V) log-probs | [V,V+H) h_new | [V+H,+L) attn_w

    // K1: attn softmax | gh | half1 | M2   (all independent given inputs)
    k_stage1<<<513, 256, 0, stream>>>(idx, hidden, enc_outs, emb,
                                      attn_W, attn_b, W_hh, b_hh, comb_W,
                                      ws, out + V + H);
    // K2: x (redundant/block) + gi + GRU -> h_new
    k_gi_gru<<<256, 256, 0, stream>>>(W_ih, b_ih, comb_b, hidden, ws, out + V);
    // K3: big matvec + per-chunk LSE pairs (2048 blocks, grid-stride)
    k_out_mv<<<NBLK3, 256, 0, stream>>>(out_W, out_b, ws,
                                        ws + WS_LOGITS, ws + WS_PAIRS);
    // K4: merge pairs + write log-softmax
    k_write<<<(V + 255) / 256, 256, 0, stream>>>(ws + WS_LOGITS, ws + WS_PAIRS, out);
}

// Round 10
// 58.529 us; speedup vs baseline: 3.3470x; 1.0171x over previous
//
#include <hip/hip_runtime.h>
#include <hip/hip_bf16.h>
#include <math.h>

#define H 1024
#define V 50257
#define L 10

#define RPC 32                         // rows per chunk in out_mv (2 halves x 4 rows/wave)
#define NCHUNK ((V + RPC - 1) / RPC)   // 1571

// ---------------- Workspace layout (floats) ----------------
#define WS_AW     0        // 16   attn weights
#define WS_GH     16       // 3072 W_hh @ h0 + b_hh
#define WS_HALF1  3104     // 1024 comb_W[:, :H] @ embedded   (no bias)
#define WS_M2T    4128     // 10*1024, layout [l][r]
#define WS_HNEW   14368    // 1024
#define WS_LOGITS 15392    // V -> ends 65649
#define WS_PAIRS  65664    // 2*NCHUNK = 3142 -> ends 68806

__device__ __forceinline__ float wave_reduce(float a) {
    #pragma unroll
    for (int off = 32; off > 0; off >>= 1) a += __shfl_down(a, off);
    return a;
}

__device__ __forceinline__ void lse_merge(float& m, float& s, float pm, float ps) {
    if (pm == -INFINITY) return;
    if (m == -INFINITY)  { m = pm; s = ps; }
    else if (pm <= m)    { s += ps * expf(pm - m); }
    else                 { s = s * expf(m - pm) + ps; m = pm; }
}

__device__ __forceinline__ float dot4(float4 a, float4 x) {
    return a.x * x.x + a.y * x.y + a.z * x.z + a.w * x.w;
}

// ========== K1: attn softmax | gh | half1 | M2  (513 blocks x 256) ==========
__global__ __launch_bounds__(256) void k_stage1(
    const int* __restrict__ idx, const float* __restrict__ hidden,
    const float* __restrict__ enc_outs, const float* __restrict__ emb,
    const float* __restrict__ attn_W, const float* __restrict__ attn_b,
    const float* __restrict__ W_hh, const float* __restrict__ b_hh,
    const float* __restrict__ comb_W,
    float* __restrict__ ws, float* __restrict__ aw_out)
{
    const int b = blockIdx.x, t = threadIdx.x;
    const int wave = t >> 6, lane = t & 63;
    const float* erow = emb + (size_t)idx[0] * H;

    if (b == 0) {
        __shared__ float s_w[16];
        const float4* e4 = (const float4*)erow;
        const float4* h4 = (const float4*)hidden;
        for (int l = wave; l < L; l += 4) {
            const float4* w4 = (const float4*)(attn_W + (size_t)l * 2 * H);
            float acc = 0.f;
            #pragma unroll
            for (int ii = 0; ii < 8; ++ii) {
                const int i = lane + 64 * ii;
                const float4 a = w4[i];
                const float4 x = (i < 256) ? e4[i] : h4[i - 256];
                acc += dot4(a, x);
            }
            acc = wave_reduce(acc);
            if (lane == 0) s_w[l] = acc + attn_b[l];
        }
        __syncthreads();
        if (t == 0) {
            float m = -1e30f;
            #pragma unroll
            for (int l = 0; l < L; ++l) m = fmaxf(m, s_w[l]);
            float s = 0.f;
            #pragma unroll
            for (int l = 0; l < L; ++l) { s_w[l] = expf(s_w[l] - m); s += s_w[l]; }
            const float inv = 1.f / s;
            #pragma unroll
            for (int l = 0; l < L; ++l) s_w[l] *= inv;
        }
        __syncthreads();
        if (t < L) { ws[WS_AW + t] = s_w[t]; aw_out[t] = s_w[t]; }
    } else if (b <= 192) {
        // gh = W_hh @ h0 + b_hh   (16 rows/block)
        const int r0 = (b - 1) * 16 + wave * 4;
        const float4* v4 = (const float4*)hidden;
        float4 hx[4];
        #pragma unroll
        for (int j = 0; j < 4; ++j) hx[j] = v4[lane + 64 * j];
        float a0 = 0.f, a1 = 0.f, a2 = 0.f, a3 = 0.f;
        const float4* w0 = (const float4*)(W_hh + (size_t)(r0 + 0) * H);
        const float4* w1 = (const float4*)(W_hh + (size_t)(r0 + 1) * H);
        const float4* w2 = (const float4*)(W_hh + (size_t)(r0 + 2) * H);
        const float4* w3 = (const float4*)(W_hh + (size_t)(r0 + 3) * H);
        #pragma unroll
        for (int j = 0; j < 4; ++j) {
            const int i = lane + 64 * j;
            a0 += dot4(w0[i], hx[j]); a1 += dot4(w1[i], hx[j]);
            a2 += dot4(w2[i], hx[j]); a3 += dot4(w3[i], hx[j]);
        }
        a0 = wave_reduce(a0); a1 = wave_reduce(a1);
        a2 = wave_reduce(a2); a3 = wave_reduce(a3);
        if (lane == 0) {
            ws[WS_GH + r0 + 0] = a0 + b_hh[r0 + 0];
            ws[WS_GH + r0 + 1] = a1 + b_hh[r0 + 1];
            ws[WS_GH + r0 + 2] = a2 + b_hh[r0 + 2];
            ws[WS_GH + r0 + 3] = a3 + b_hh[r0 + 3];
        }
    } else if (b <= 256) {
        // half1 = comb_W[:, :H] @ embedded   (16 rows/block)
        const int r0 = (b - 193) * 16 + wave * 4;
        const float4* e4 = (const float4*)erow;
        float4 ex[4];
        #pragma unroll
        for (int j = 0; j < 4; ++j) ex[j] = e4[lane + 64 * j];
        float a0 = 0.f, a1 = 0.f, a2 = 0.f, a3 = 0.f;
        const float4* w0 = (const float4*)(comb_W + (size_t)(r0 + 0) * 2 * H);
        const float4* w1 = (const float4*)(comb_W + (size_t)(r0 + 1) * 2 * H);
        const float4* w2 = (const float4*)(comb_W + (size_t)(r0 + 2) * 2 * H);
        const float4* w3 = (const float4*)(comb_W + (size_t)(r0 + 3) * 2 * H);
        #pragma unroll
        for (int j = 0; j < 4; ++j) {
            const int i = lane + 64 * j;
            a0 += dot4(w0[i], ex[j]); a1 += dot4(w1[i], ex[j]);
            a2 += dot4(w2[i], ex[j]); a3 += dot4(w3[i], ex[j]);
        }
        a0 = wave_reduce(a0); a1 = wave_reduce(a1);
        a2 = wave_reduce(a2); a3 = wave_reduce(a3);
        if (lane == 0) {
            ws[WS_HALF1 + r0 + 0] = a0; ws[WS_HALF1 + r0 + 1] = a1;
            ws[WS_HALF1 + r0 + 2] = a2; ws[WS_HALF1 + r0 + 3] = a3;
        }
    } else {
        // M2T[l][r] = dot(comb_W[r, H:2H], enc_outs[l]),  one row r per wave
        const int r = (b - 257) * 4 + wave;
        const float4* w4 = (const float4*)(comb_W + (size_t)r * 2 * H + H);
        float acc[L];
        #pragma unroll
        for (int l = 0; l < L; ++l) acc[l] = 0.f;
        #pragma unroll
        for (int j = 0; j < 4; ++j) {
            const int i = lane + 64 * j;
            const float4 w = w4[i];
            #pragma unroll
            for (int l = 0; l < L; ++l) {
                const float4 e = ((const float4*)(enc_outs + l * H))[i];
                acc[l] += dot4(w, e);
            }
        }
        #pragma unroll
        for (int l = 0; l < L; ++l) {
            const float r_ = wave_reduce(acc[l]);
            if (lane == 0) ws[WS_M2T + l * 1024 + r] = r_;
        }
    }
}

// ========== K2: x (redundant per block) + gi + GRU  (256 blocks x 256) ==========
__global__ __launch_bounds__(256) void k_gi_gru(
    const float* __restrict__ W_ih, const float* __restrict__ b_ih,
    const float* __restrict__ comb_b, const float* __restrict__ hidden,
    float* __restrict__ ws, float* __restrict__ h_out)
{
    __shared__ float sx[1024];
    const int t = threadIdx.x;
    #pragma unroll
    for (int q = 0; q < 4; ++q) {
        const int e = t + q * 256;
        float acc = ws[WS_HALF1 + e] + comb_b[e];
        #pragma unroll
        for (int l = 0; l < L; ++l)
            acc += ws[WS_M2T + l * 1024 + e] * ws[WS_AW + l];
        sx[e] = fmaxf(acc, 0.f);
    }
    __syncthreads();
    const int wave = t >> 6, lane = t & 63;
    const int u = blockIdx.x * 4 + wave;
    const float4* x4 = (const float4*)sx;
    const float4* w0 = (const float4*)(W_ih + (size_t)u * H);
    const float4* w1 = (const float4*)(W_ih + (size_t)(H + u) * H);
    const float4* w2 = (const float4*)(W_ih + (size_t)(2 * H + u) * H);
    float a0 = 0.f, a1 = 0.f, a2 = 0.f;
    #pragma unroll
    for (int q = 0; q < 4; ++q) {
        const int i = lane + 64 * q;
        const float4 x = x4[i];
        a0 += dot4(w0[i], x);
        a1 += dot4(w1[i], x);
        a2 += dot4(w2[i], x);
    }
    a0 = wave_reduce(a0); a1 = wave_reduce(a1); a2 = wave_reduce(a2);
    if (lane == 0) {
        const float ir  = a0 + b_ih[u];
        const float iz  = a1 + b_ih[H + u];
        const float in_ = a2 + b_ih[2 * H + u];
        const float hr = ws[WS_GH + u];
        const float hz = ws[WS_GH + H + u];
        const float hn = ws[WS_GH + 2 * H + u];
        const float r = 1.f / (1.f + expf(-(ir + hr)));
        const float z = 1.f / (1.f + expf(-(iz + hz)));
        const float n = tanhf(in_ + r * hn);
        const float h = (1.f - z) * n + z * hidden[u];
        ws[WS_HNEW + u] = h;
        h_out[u] = h;
    }
}

// ========== K3: out matvec, RPC=32 (two 16-row halves, R6 inner body) ==========
__global__ __launch_bounds__(256) void k_out_mv(
    const float* __restrict__ out_W, const float* __restrict__ out_b,
    const float* __restrict__ ws_in, float* __restrict__ logits,
    float* __restrict__ pairs)
{
    __shared__ float sm[4], ss[4];
    const int wave = threadIdx.x >> 6, lane = threadIdx.x & 63;
    const float4* v4 = (const float4*)(ws_in + WS_HNEW);
    float4 hx[4];
    #pragma unroll
    for (int j = 0; j < 4; ++j) hx[j] = v4[lane + 64 * j];

    float wm = -INFINITY, wsum = 0.f;
    #pragma unroll
    for (int half = 0; half < 2; ++half) {
        const int base = blockIdx.x * RPC + half * 16 + wave * 4;
        #pragma unroll
        for (int k = 0; k < 4; ++k) {
            const int row = base + k;
            if (row < V) {
                const float4* w4 = (const float4*)(out_W + (size_t)row * H);
                float acc = 0.f;
                #pragma unroll
                for (int j = 0; j < 4; ++j) acc += dot4(w4[lane + 64 * j], hx[j]);
                acc = wave_reduce(acc);
                if (lane == 0) {
                    const float val = acc + out_b[row];
                    logits[row] = val;
                    lse_merge(wm, wsum, val, 1.f);
                }
            }
        }
    }
    if (lane == 0) { sm[wave] = wm; ss[wave] = wsum; }
    __syncthreads();
    if (threadIdx.x == 0) {
        float m = -INFINITY, s = 0.f;
        #pragma unroll
        for (int w = 0; w < 4; ++w) lse_merge(m, s, sm[w], ss[w]);
        pairs[2 * blockIdx.x] = m; pairs[2 * blockIdx.x + 1] = s;
    }
}

// ========== K4: redundant pair merge + write log-softmax ==========
__global__ __launch_bounds__(256) void k_write(
    const float* __restrict__ logits, const float* __restrict__ pairs,
    float* __restrict__ out)
{
    __shared__ float sm[256], ss[256];
    const int t = threadIdx.x;
    float m = -INFINITY, s = 0.f;
    for (int i = t; i < NCHUNK; i += 256) lse_merge(m, s, pairs[2 * i], pairs[2 * i + 1]);
    sm[t] = m; ss[t] = s; __syncthreads();
    for (int k = 128; k > 0; k >>= 1) {
        if (t < k) {
            float mm = sm[t], ssv = ss[t];
            lse_merge(mm, ssv, sm[t + k], ss[t + k]);
            sm[t] = mm; ss[t] = ssv;
        }
        __syncthreads();
    }
    const float M = sm[0], LS = logf(ss[0]);
    const int i = blockIdx.x * 256 + t;
    if (i < V) out[i] = logits[i] - M - LS;
}

extern "C" void kernel_launch(void* const* d_in, const int* in_sizes, int n_in,
                              void* d_out, int out_size, void* d_ws, size_t ws_size,
                              hipStream_t stream) {
    const int*   idx      = (const int*)  d_in[0];
    const float* hidden   = (const float*)d_in[1];
    const float* enc_outs = (const float*)d_in[3];
    const float* emb      = (const float*)d_in[4];
    const float* attn_W   = (const float*)d_in[5];
    const float* attn_b   = (const float*)d_in[6];
    const float* comb_W   = (const float*)d_in[7];
    const float* comb_b   = (const float*)d_in[8];
    const float* W_ih     = (const float*)d_in[9];
    const float* W_hh     = (const float*)d_in[10];
    const float* b_ih     = (const float*)d_in[11];
    const float* b_hh     = (const float*)d_in[12];
    const float* out_W    = (const float*)d_in[13];
    const float* out_b    = (const float*)d_in[14];

    float* ws  = (float*)d_ws;
    float* out = (float*)d_out;   // [0,V) log-probs | [V,V+H) h_new | [V+H,+L) attn_w

    // K1: attn softmax | gh | half1 | M2   (all independent given inputs)
    k_stage1<<<513, 256, 0, stream>>>(idx, hidden, enc_outs, emb,
                                      attn_W, attn_b, W_hh, b_hh, comb_W,
                                      ws, out + V + H);
    // K2: x (redundant/block) + gi + GRU -> h_new
    k_gi_gru<<<256, 256, 0, stream>>>(W_ih, b_ih, comb_b, hidden, ws, out + V);
    // K3: big matvec + per-chunk LSE pairs  (RPC=32 -> 1571 blocks)
    k_out_mv<<<NCHUNK, 256, 0, stream>>>(out_W, out_b, ws,
                                         ws + WS_LOGITS, ws + WS_PAIRS);
    // K4: merge pairs + write log-softmax
    k_write<<<(V + 255) / 256, 256, 0, stream>>>(ws + WS_LOGITS, ws + WS_PAIRS, out);
}